// Round 1
// baseline (21987.254 us; speedup 1.0000x reference)
//
#include <hip/hip_runtime.h>
#include <hip/hip_bf16.h>

// LSTM: B=64, S=1024, I=256, H=512, 2 layers. fp32 in/out.
// Persistent kernel, 128 WGs (64/layer), layer-1 pipelined behind layer-0.
// Round-1 redesign: NO fences / cache-maintenance in the step loop.
//  - h exchange via sc0 sc1 (L1/L2-bypass) stores/loads to L3-resident rings
//  - relaxed agent-scope flag atomics, per-wave per-batch-tile counters
//  - no __syncthreads() in the loop (waves sync independently)
//  - out0 buffer eliminated: layer-1 reads h0 ring, acks via fC flags
//  - weights pre-converted fp32->bf16 once into coalesced per-WG frag cache

#define BB 64
#define SS 1024
#define HH 512
#define NWG 64   // WGs per layer

typedef unsigned short u16;
typedef __attribute__((ext_vector_type(8))) short bf16x8;
typedef __attribute__((ext_vector_type(4))) float f32x4;

__device__ __forceinline__ bf16x8 ldfrag(const u16* p) {
  return *reinterpret_cast<const bf16x8*>(p);
}
__device__ __forceinline__ u16 f2bf(float f) {
  __hip_bfloat16 h = __float2bfloat16(f);
  return *reinterpret_cast<u16*>(&h);
}
__device__ __forceinline__ bf16x8 cvt8(const float* p) {
  const f32x4* v = reinterpret_cast<const f32x4*>(p);
  f32x4 a = v[0], b = v[1];
  bf16x8 r;
  r[0] = (short)f2bf(a[0]); r[1] = (short)f2bf(a[1]);
  r[2] = (short)f2bf(a[2]); r[3] = (short)f2bf(a[3]);
  r[4] = (short)f2bf(b[0]); r[5] = (short)f2bf(b[1]);
  r[6] = (short)f2bf(b[2]); r[7] = (short)f2bf(b[3]);
  return r;
}
__device__ __forceinline__ float sigm(float x) { return 1.0f / (1.0f + __expf(-x)); }
__device__ __forceinline__ float tanh_f(float x) { return 2.0f / (1.0f + __expf(-2.0f * x)) - 1.0f; }

// ---- device-coherent access: bypass L1/L2, data lives at L3/MALL ----
__device__ __forceinline__ bf16x8 ldg_cv(const u16* p) {
  bf16x8 r;
  asm volatile("global_load_dwordx4 %0, %1, off sc0 sc1"
               : "=v"(r) : "v"(p) : "memory");
  return r;
}
__device__ __forceinline__ void stg_cv16(u16* p, u16 v) {
  unsigned int w = v;
  asm volatile("global_store_short %0, %1, off sc0 sc1"
               :: "v"(p), "v"(w) : "memory");
}
__device__ __forceinline__ int ld_flag(int* p) {
  return __hip_atomic_load(p, __ATOMIC_RELAXED, __HIP_MEMORY_SCOPE_AGENT);
}
__device__ __forceinline__ void add_flag(int* p) {
  __hip_atomic_fetch_add(p, 1, __ATOMIC_RELAXED, __HIP_MEMORY_SCOPE_AGENT);
}
__device__ __forceinline__ void waitflag(int* p, int probe) {
  if (probe >= NWG) return;
  while (ld_flag(p) < NWG) __builtin_amdgcn_s_sleep(1);
}
#define VMCNT0() asm volatile("s_waitcnt vmcnt(0)" ::: "memory")

#define MFMA(a, b, c) __builtin_amdgcn_mfma_f32_16x16x32_bf16((a), (b), (c), 0, 0, 0)

// Convert this WG's weight slice fp32->bf16 into a coalesced fragment cache.
// Slot (iter, lane) holds exactly the 16B fragment lane `lane` reads for iter.
template<int KIN>
__device__ __forceinline__ void conv_weights(
    const float* __restrict__ Wih, const float* __restrict__ Whh,
    u16* __restrict__ wcg, int wrow0, int wrow1, int q, int lane, int wv)
{
  constexpr int KITER = KIN / 32;
  constexpr int ITERS = (KITER + 16) * 2;
  for (int iter = wv; iter < ITERS; iter += 4) {
    const int half = iter >> 1;
    const int wrow = (iter & 1) ? wrow1 : wrow0;
    const float* src = (half < KITER)
        ? (Wih + (size_t)wrow * KIN + half * 32 + q * 8)
        : (Whh + (size_t)wrow * HH + (half - KITER) * 32 + q * 8);
    bf16x8 f = cvt8(src);
    *reinterpret_cast<bf16x8*>(wcg + ((size_t)iter * 64 + lane) * 8) = f;
  }
}

__device__ __forceinline__ void run_l0(
    const float* __restrict__ x,
    const float* __restrict__ Wih, const float* __restrict__ Whh,
    const float* __restrict__ bih, const float* __restrict__ bhh,
    float* __restrict__ hn, float* __restrict__ cn,
    u16* __restrict__ R0, int* __restrict__ fH0, int* __restrict__ fC,
    u16* __restrict__ wcg)
{
  const int g = blockIdx.x & (NWG - 1);
  const int tid = threadIdx.x;
  const int wv = tid >> 6;
  const int lane = tid & 63;
  const int q = lane >> 4;
  const int n16 = lane & 15;
  const int g8 = g * 8;
  const int c0 = n16, c1 = 16 + n16;
  const int wrow0 = ((c0 >> 3) * HH) + g8 + (c0 & 7);
  const int wrow1 = ((c1 >> 3) * HH) + g8 + (c1 & 7);
  constexpr int KIN = 256, KITER = 8;

  conv_weights<KIN>(Wih, Whh, wcg, wrow0, wrow1, q, lane, wv);
  __syncthreads();

  const float bias0 = bih[wrow0] + bhh[wrow0];
  const float bias1 = bih[wrow1] + bhh[wrow1];
  const int arow = wv * 16 + n16;
  const int hcol = g8 + n16;      // valid for n16 < 8

  float cst[4] = {0.f, 0.f, 0.f, 0.f};

  for (int t = 0; t < SS; ++t) {
    // early probes (latency hidden under the x-GEMM)
    int pC = (t >= 4) ? ld_flag(&fC[(t - 4) * 4 + wv]) : NWG;
    int pH = (t >= 1) ? ld_flag(&fH0[(t - 1) * 4 + wv]) : NWG;

    f32x4 acc0 = {0.f, 0.f, 0.f, 0.f};
    f32x4 acc1 = {0.f, 0.f, 0.f, 0.f};

    // input contribution (no dependence on any flag)
    const float* xp = x + (size_t)arow * SS * KIN + (size_t)t * KIN + q * 8;
#pragma unroll
    for (int ks = 0; ks < KITER; ++ks) {
      bf16x8 a  = cvt8(xp + ks * 32);
      bf16x8 b0 = ldfrag(wcg + ((size_t)(2 * ks + 0) * 64 + lane) * 8);
      bf16x8 b1 = ldfrag(wcg + ((size_t)(2 * ks + 1) * 64 + lane) * 8);
      acc0 = MFMA(a, b0, acc0);
      acc1 = MFMA(a, b1, acc1);
    }

    // recurrent contribution: wait for peers' h_{t-1}, read via L3 bypass
    if (t >= 1) waitflag(&fH0[(t - 1) * 4 + wv], pH);
    const u16* hr = R0 + (size_t)((t + 3) & 3) * BB * HH + (size_t)arow * HH + q * 8;
    bf16x8 hf[16];
#pragma unroll
    for (int ks = 0; ks < 16; ++ks) hf[ks] = ldg_cv(hr + ks * 32);
    VMCNT0();
    __builtin_amdgcn_sched_barrier(0);
#pragma unroll
    for (int ks = 0; ks < 16; ++ks) {
      bf16x8 b0 = ldfrag(wcg + ((size_t)(2 * (KITER + ks) + 0) * 64 + lane) * 8);
      bf16x8 b1 = ldfrag(wcg + ((size_t)(2 * (KITER + ks) + 1) * 64 + lane) * 8);
      acc0 = MFMA(hf[ks], b0, acc0);
      acc1 = MFMA(hf[ks], b1, acc1);
    }

    float a0[4], a1[4], p0[4], p1[4];
#pragma unroll
    for (int r = 0; r < 4; ++r) { a0[r] = acc0[r] + bias0; a1[r] = acc1[r] + bias1; }
#pragma unroll
    for (int r = 0; r < 4; ++r) {
      p0[r] = __shfl_xor(a0[r], 8, 64);   // f pre-activations (for n16<8)
      p1[r] = __shfl_xor(a1[r], 8, 64);   // o pre-activations
    }

    // ring-slot reuse gate: layer-1 must have consumed h0_{t-4}
    if (t >= 4) waitflag(&fC[(t - 4) * 4 + wv], pC);

    if (n16 < 8) {
      u16* hw = R0 + (size_t)(t & 3) * BB * HH;
#pragma unroll
      for (int r = 0; r < 4; ++r) {
        const int b = wv * 16 + q * 4 + r;
        float ig = sigm(a0[r]);
        float fg = sigm(p0[r]);
        float gg = tanh_f(a1[r]);
        float og = sigm(p1[r]);
        float cv = fg * cst[r] + ig * gg;
        cst[r] = cv;
        float hv = og * tanh_f(cv);
        stg_cv16(hw + (size_t)b * HH + hcol, f2bf(hv));
        if (t == SS - 1) {
          hn[(size_t)b * HH + hcol] = hv;
          cn[(size_t)b * HH + hcol] = cv;
        }
      }
    }
    VMCNT0();                                  // h stores acked at L3
    if (lane == 0) add_flag(&fH0[t * 4 + wv]); // publish h0_t (rows of tile wv)
  }
}

__device__ __forceinline__ void run_l1(
    const float* __restrict__ Wih, const float* __restrict__ Whh,
    const float* __restrict__ bih, const float* __restrict__ bhh,
    float* __restrict__ out1, float* __restrict__ hn, float* __restrict__ cn,
    const u16* __restrict__ R0, u16* __restrict__ R1,
    int* __restrict__ fH0, int* __restrict__ fH1, int* __restrict__ fC,
    u16* __restrict__ wcg)
{
  const int g = blockIdx.x & (NWG - 1);
  const int tid = threadIdx.x;
  const int wv = tid >> 6;
  const int lane = tid & 63;
  const int q = lane >> 4;
  const int n16 = lane & 15;
  const int g8 = g * 8;
  const int c0 = n16, c1 = 16 + n16;
  const int wrow0 = ((c0 >> 3) * HH) + g8 + (c0 & 7);
  const int wrow1 = ((c1 >> 3) * HH) + g8 + (c1 & 7);
  constexpr int KITER = 16;  // KIN = 512

  conv_weights<512>(Wih, Whh, wcg, wrow0, wrow1, q, lane, wv);
  __syncthreads();

  const float bias0 = bih[wrow0] + bhh[wrow0];
  const float bias1 = bih[wrow1] + bhh[wrow1];
  const int arow = wv * 16 + n16;
  const int hcol = g8 + n16;

  float cst[4] = {0.f, 0.f, 0.f, 0.f};

  for (int t = 0; t < SS; ++t) {
    int pD = ld_flag(&fH0[t * 4 + wv]);
    int pH = (t >= 1) ? ld_flag(&fH1[(t - 1) * 4 + wv]) : NWG;

    // producer's h0_t
    waitflag(&fH0[t * 4 + wv], pD);
    const u16* h0r = R0 + (size_t)(t & 3) * BB * HH + (size_t)arow * HH + q * 8;
    bf16x8 xf[16];
#pragma unroll
    for (int ks = 0; ks < 16; ++ks) xf[ks] = ldg_cv(h0r + ks * 32);
    VMCNT0();                                  // h0 is in registers:
    if (lane == 0) add_flag(&fC[t * 4 + wv]);  // release ring slot early
    __builtin_amdgcn_sched_barrier(0);

    f32x4 acc0 = {0.f, 0.f, 0.f, 0.f};
    f32x4 acc1 = {0.f, 0.f, 0.f, 0.f};
#pragma unroll
    for (int ks = 0; ks < 16; ++ks) {
      bf16x8 b0 = ldfrag(wcg + ((size_t)(2 * ks + 0) * 64 + lane) * 8);
      bf16x8 b1 = ldfrag(wcg + ((size_t)(2 * ks + 1) * 64 + lane) * 8);
      acc0 = MFMA(xf[ks], b0, acc0);
      acc1 = MFMA(xf[ks], b1, acc1);
    }

    // own recurrent h1_{t-1}
    if (t >= 1) waitflag(&fH1[(t - 1) * 4 + wv], pH);
    const u16* h1r = R1 + (size_t)((t + 1) & 1) * BB * HH + (size_t)arow * HH + q * 8;
    bf16x8 hf[16];
#pragma unroll
    for (int ks = 0; ks < 16; ++ks) hf[ks] = ldg_cv(h1r + ks * 32);
    VMCNT0();
    __builtin_amdgcn_sched_barrier(0);
#pragma unroll
    for (int ks = 0; ks < 16; ++ks) {
      bf16x8 b0 = ldfrag(wcg + ((size_t)(2 * (KITER + ks) + 0) * 64 + lane) * 8);
      bf16x8 b1 = ldfrag(wcg + ((size_t)(2 * (KITER + ks) + 1) * 64 + lane) * 8);
      acc0 = MFMA(hf[ks], b0, acc0);
      acc1 = MFMA(hf[ks], b1, acc1);
    }

    float a0[4], a1[4], p0[4], p1[4];
#pragma unroll
    for (int r = 0; r < 4; ++r) { a0[r] = acc0[r] + bias0; a1[r] = acc1[r] + bias1; }
#pragma unroll
    for (int r = 0; r < 4; ++r) {
      p0[r] = __shfl_xor(a0[r], 8, 64);
      p1[r] = __shfl_xor(a1[r], 8, 64);
    }

    if (n16 < 8) {
      u16* hw = R1 + (size_t)(t & 1) * BB * HH;
#pragma unroll
      for (int r = 0; r < 4; ++r) {
        const int b = wv * 16 + q * 4 + r;
        float ig = sigm(a0[r]);
        float fg = sigm(p0[r]);
        float gg = tanh_f(a1[r]);
        float og = sigm(p1[r]);
        float cv = fg * cst[r] + ig * gg;
        cst[r] = cv;
        float hv = og * tanh_f(cv);
        stg_cv16(hw + (size_t)b * HH + hcol, f2bf(hv));
        out1[((size_t)b * SS + t) * HH + hcol] = hv;   // plain: host-read only
        if (t == SS - 1) {
          hn[(size_t)b * HH + hcol] = hv;
          cn[(size_t)b * HH + hcol] = cv;
        }
      }
    }
    VMCNT0();
    if (lane == 0) add_flag(&fH1[t * 4 + wv]);
  }
}

__global__ __launch_bounds__(256, 1) void lstm_persist(
    const float* __restrict__ x,
    const float* __restrict__ Wih0, const float* __restrict__ Whh0,
    const float* __restrict__ bih0, const float* __restrict__ bhh0,
    const float* __restrict__ Wih1, const float* __restrict__ Whh1,
    const float* __restrict__ bih1, const float* __restrict__ bhh1,
    float* out1, float* hn, float* cn,
    u16* R0, u16* R1,
    int* fH0, int* fH1, int* fC,
    u16* wc0, u16* wc1)
{
  const int g = blockIdx.x & (NWG - 1);
  if ((blockIdx.x >> 6) == 0) {
    run_l0(x, Wih0, Whh0, bih0, bhh0, hn, cn,
           R0, fH0, fC, wc0 + (size_t)g * 48 * 512);
  } else {
    run_l1(Wih1, Whh1, bih1, bhh1, out1,
           hn + (size_t)BB * HH, cn + (size_t)BB * HH,
           R0, R1, fH0, fH1, fC, wc1 + (size_t)g * 64 * 512);
  }
}

extern "C" void kernel_launch(void* const* d_in, const int* in_sizes, int n_in,
                              void* d_out, int out_size, void* d_ws, size_t ws_size,
                              hipStream_t stream) {
  const float* x    = (const float*)d_in[0];
  const float* Wih0 = (const float*)d_in[1];
  const float* Whh0 = (const float*)d_in[2];
  const float* bih0 = (const float*)d_in[3];
  const float* bhh0 = (const float*)d_in[4];
  const float* Wih1 = (const float*)d_in[5];
  const float* Whh1 = (const float*)d_in[6];
  const float* bih1 = (const float*)d_in[7];
  const float* bhh1 = (const float*)d_in[8];

  float* out  = (float*)d_out;
  float* out1 = out;                                  // (64,1024,512) fp32
  float* hn   = out + (size_t)BB * SS * HH;           // (2,64,512) fp32
  float* cn   = hn + 2 * (size_t)BB * HH;             // (2,64,512) fp32

  char* ws = (char*)d_ws;
  const size_t R0_B  = 4ull * BB * HH * 2;            // 262144: 4-deep h0 ring
  const size_t R1_B  = 2ull * BB * HH * 2;            // 131072: 2-deep h1 ring
  const size_t F_B   = 3ull * SS * 4 * 4;             // 49152: fH0,fH1,fC
  const size_t WC0_B = (size_t)NWG * 48 * 512 * 2;    // 3 MiB bf16 frag cache L0
  const size_t WC1_B = (size_t)NWG * 64 * 512 * 2;    // 4 MiB bf16 frag cache L1
  if (ws_size < R0_B + R1_B + F_B + WC0_B + WC1_B) return;

  u16* R0  = (u16*)ws;
  u16* R1  = (u16*)(ws + R0_B);
  int* fH0 = (int*)(ws + R0_B + R1_B);
  int* fH1 = fH0 + SS * 4;
  int* fC  = fH1 + SS * 4;
  u16* wc0 = (u16*)(ws + R0_B + R1_B + F_B);
  u16* wc1 = wc0 + (size_t)NWG * 48 * 512;

  // zero rings (h0=c0=0 initial state) and all flags
  hipMemsetAsync(ws, 0, R0_B + R1_B + F_B, stream);

  lstm_persist<<<dim3(2 * NWG), dim3(256), 0, stream>>>(
      x, Wih0, Whh0, bih0, bhh0, Wih1, Whh1, bih1, bhh1,
      out1, hn, cn, R0, R1, fH0, fH1, fC, wc0, wc1);
}

// Round 4
// 15181.699 us; speedup vs baseline: 1.4483x; 1.4483x over previous
//
#include <hip/hip_runtime.h>
#include <hip/hip_bf16.h>

// LSTM: B=64, S=1024, I=256, H=512, 2 layers. fp32 in/out.
// Persistent kernel, 128 WGs (64/layer), layer-1 pipelined behind layer-0.
// Round-4: minimal delta from round-1 (last passing, 22ms).
//  - VECTOR flags: producer g stores flag[t][wv][g]=1 (plain sc0 sc1 dword);
//    consumer wave polls 64 words with ONE coalesced 64-lane sc0 sc1 load
//    + __all.  No atomic RMW serialization, no poll-storm.
//  - LDS <= 3KB (transpose staging only) -- no big static LDS (r3 crash risk)
//  - weights in global bf16 frag cache (round-1 proven mechanism)
//  - h0 ring depth 64 (4MB): fC wait has 64-step slack, off critical path
//  - bounded spins (~2.7ms/wait): fail-visible, cannot trip the watchdog
//  - out1/hn/cn stores AFTER the flag release (host-only consumers)

#define BB 64
#define SS 1024
#define HH 512
#define NWG 64      // WGs per layer
#define RDEPTH 64   // h0 ring depth (steps)

typedef unsigned short u16;
typedef __attribute__((ext_vector_type(8))) short bf16x8;
typedef __attribute__((ext_vector_type(4))) float f32x4;

__device__ __forceinline__ bf16x8 ldfrag(const u16* p) {
  return *reinterpret_cast<const bf16x8*>(p);
}
__device__ __forceinline__ u16 f2bf(float f) {
  __hip_bfloat16 h = __float2bfloat16(f);
  return *reinterpret_cast<u16*>(&h);
}
__device__ __forceinline__ bf16x8 cvt8(const float* p) {
  const f32x4* v = reinterpret_cast<const f32x4*>(p);
  f32x4 a = v[0], b = v[1];
  bf16x8 r;
  r[0] = (short)f2bf(a[0]); r[1] = (short)f2bf(a[1]);
  r[2] = (short)f2bf(a[2]); r[3] = (short)f2bf(a[3]);
  r[4] = (short)f2bf(b[0]); r[5] = (short)f2bf(b[1]);
  r[6] = (short)f2bf(b[2]); r[7] = (short)f2bf(b[3]);
  return r;
}
__device__ __forceinline__ float sigm(float x) { return 1.0f / (1.0f + __expf(-x)); }
__device__ __forceinline__ float tanh_f(float x) { return 2.0f / (1.0f + __expf(-2.0f * x)) - 1.0f; }

// ---- MALL-coherent data access (scope-encoded cache bypass) ----
__device__ __forceinline__ bf16x8 ldg_cv(const u16* p) {
  bf16x8 r;
  asm volatile("global_load_dwordx4 %0, %1, off sc0 sc1"
               : "=v"(r) : "v"(p) : "memory");
  return r;
}
__device__ __forceinline__ void stg_cv(u16* p, bf16x8 v) {
  asm volatile("global_store_dwordx4 %0, %1, off sc0 sc1"
               :: "v"(p), "v"(v) : "memory");
}
// ---- vector flags: one word per producer, one wave-wide poll ----
__device__ __forceinline__ void set_flag(int* p) {
  int one = 1;
  asm volatile("global_store_dword %0, %1, off sc0 sc1"
               :: "v"(p), "v"(one) : "memory");
}
__device__ __forceinline__ void waitflag_vec(const int* row) {
  const int lane = threadIdx.x & 63;
  const int* p = row + lane;          // lane i watches producer WG i
  for (int it = 0; it < (1 << 13); ++it) {   // ~2.7ms cap: fail, don't hang
    int v;
    asm volatile("global_load_dword %0, %1, off sc0 sc1"
                 : "=v"(v) : "v"(p) : "memory");
    asm volatile("s_waitcnt vmcnt(0)" ::: "memory");
    if (__all(v != 0)) return;
    __builtin_amdgcn_s_sleep(2);
  }
}
__device__ __forceinline__ int* frow(int* base, int t, int wv) {
  return base + ((size_t)(t * 4 + wv) << 6);   // 64 ints per (t,wv) row
}
#define VMCNT0() do { \
  asm volatile("s_waitcnt vmcnt(0)" ::: "memory"); \
  __builtin_amdgcn_sched_barrier(0); \
} while (0)
#define LGKM0() do { \
  asm volatile("s_waitcnt lgkmcnt(0)" ::: "memory"); \
  __builtin_amdgcn_sched_barrier(0); \
} while (0)

#define MFMA(a, b, c) __builtin_amdgcn_mfma_f32_16x16x32_bf16((a), (b), (c), 0, 0, 0)

// Convert this WG's weight slice fp32->bf16 into a GLOBAL fragment cache.
// Slot (iter, lane) holds exactly the 16B fragment lane `lane` reads for iter.
template<int KIN>
__device__ __forceinline__ void conv_weights(
    const float* __restrict__ Wih, const float* __restrict__ Whh,
    u16* __restrict__ wcg, int wrow0, int wrow1, int q, int lane, int wv)
{
  constexpr int KITER = KIN / 32;
  constexpr int ITERS = (KITER + 16) * 2;
  for (int iter = wv; iter < ITERS; iter += 4) {
    const int half = iter >> 1;
    const int wrow = (iter & 1) ? wrow1 : wrow0;
    const float* src = (half < KITER)
        ? (Wih + (size_t)wrow * KIN + half * 32 + q * 8)
        : (Whh + (size_t)wrow * HH + (half - KITER) * 32 + q * 8);
    bf16x8 f = cvt8(src);
    *reinterpret_cast<bf16x8*>(wcg + ((size_t)iter * 64 + lane) * 8) = f;
  }
}

__device__ __forceinline__ void run_l0(
    const float* __restrict__ x,
    const float* __restrict__ Wih, const float* __restrict__ Whh,
    const float* __restrict__ bih, const float* __restrict__ bhh,
    float* __restrict__ hn, float* __restrict__ cn,
    u16* __restrict__ R0, int* __restrict__ fH0, int* __restrict__ fC,
    u16* __restrict__ wcg)
{
  __shared__ u16 hT[4 * 16 * 8];      // per-wave transpose staging (1KB)
  const int g = blockIdx.x & (NWG - 1);
  const int tid = threadIdx.x;
  const int wv = tid >> 6;
  const int lane = tid & 63;
  const int q = lane >> 4;
  const int n16 = lane & 15;
  const int g8 = g * 8;
  const int c0 = n16, c1 = 16 + n16;
  const int wrow0 = ((c0 >> 3) * HH) + g8 + (c0 & 7);
  const int wrow1 = ((c1 >> 3) * HH) + g8 + (c1 & 7);
  constexpr int KIN = 256, KITER = 8;

  conv_weights<KIN>(Wih, Whh, wcg, wrow0, wrow1, q, lane, wv);
  __syncthreads();

  const float bias0 = bih[wrow0] + bhh[wrow0];
  const float bias1 = bih[wrow1] + bhh[wrow1];
  const int arow = wv * 16 + n16;
  const int hcol = g8 + n16;      // valid for n16 < 8
  const int l16 = lane & 15;

  float cst[4] = {0.f, 0.f, 0.f, 0.f};
  float hvl[4], cvl[4];

  for (int t = 0; t < SS; ++t) {
    // ---- x loads + cvt (flag-independent) ----
    bf16x8 xa[KITER];
    const float* xp = x + (size_t)arow * SS * KIN + (size_t)t * KIN + q * 8;
#pragma unroll
    for (int ks = 0; ks < KITER; ++ks) xa[ks] = cvt8(xp + ks * 32);

    // ---- wait peers' h_{t-1} (one vector poll), issue coherent h loads ----
    bf16x8 hf[16];
    if (t > 0) {
      waitflag_vec(frow(fH0, t - 1, wv));
      const u16* hr = R0 + (size_t)((t - 1) & (RDEPTH - 1)) * BB * HH
                    + (size_t)arow * HH + q * 8;
#pragma unroll
      for (int ks = 0; ks < 16; ++ks) hf[ks] = ldg_cv(hr + ks * 32);
    }

    // ---- x GEMM (h loads in flight), frags from global cache ----
    f32x4 acc0 = {0.f, 0.f, 0.f, 0.f};
    f32x4 acc1 = {0.f, 0.f, 0.f, 0.f};
#pragma unroll
    for (int ks = 0; ks < KITER; ++ks) {
      bf16x8 b0 = ldfrag(wcg + ((size_t)(2 * ks + 0) * 64 + lane) * 8);
      bf16x8 b1 = ldfrag(wcg + ((size_t)(2 * ks + 1) * 64 + lane) * 8);
      acc0 = MFMA(xa[ks], b0, acc0);
      acc1 = MFMA(xa[ks], b1, acc1);
    }

    // ---- h GEMM ----
    if (t > 0) {
      VMCNT0();
#pragma unroll
      for (int ks = 0; ks < 16; ++ks) {
        bf16x8 b0 = ldfrag(wcg + ((size_t)(2 * (KITER + ks) + 0) * 64 + lane) * 8);
        bf16x8 b1 = ldfrag(wcg + ((size_t)(2 * (KITER + ks) + 1) * 64 + lane) * 8);
        acc0 = MFMA(hf[ks], b0, acc0);
        acc1 = MFMA(hf[ks], b1, acc1);
      }
    }

    // ---- gates / cell update ----
    float a0[4], a1[4], p0[4], p1[4];
#pragma unroll
    for (int r = 0; r < 4; ++r) { a0[r] = acc0[r] + bias0; a1[r] = acc1[r] + bias1; }
#pragma unroll
    for (int r = 0; r < 4; ++r) {
      p0[r] = __shfl_xor(a0[r], 8, 64);   // f pre-activations (for n16<8)
      p1[r] = __shfl_xor(a1[r], 8, 64);   // o pre-activations
    }

    if (n16 < 8) {
#pragma unroll
      for (int r = 0; r < 4; ++r) {
        float ig = sigm(a0[r]);
        float fg = sigm(p0[r]);
        float gg = tanh_f(a1[r]);
        float og = sigm(p1[r]);
        float cv = fg * cst[r] + ig * gg;
        cst[r] = cv;
        float hv = og * tanh_f(cv);
        hvl[r] = hv; cvl[r] = cv;
        hT[wv * 128 + (q * 4 + r) * 8 + n16] = f2bf(hv);
      }
    }
    LGKM0();   // per-wave: transpose writes visible to reader lanes

    // ---- ring-slot reuse gate (64-step slack, normally pre-satisfied) ----
    if (t >= RDEPTH) waitflag_vec(frow(fC, t - RDEPTH, wv));

    // ---- coherent ring store: 16 x 16B per wave ----
    if (lane < 16) {
      bf16x8 hv8 = *reinterpret_cast<bf16x8*>(&hT[wv * 128 + l16 * 8]);
      stg_cv(R0 + (size_t)(t & (RDEPTH - 1)) * BB * HH
                + (size_t)(wv * 16 + l16) * HH + g8, hv8);
    }
    VMCNT0();                                        // stores acked at MALL
    if (lane == 0) set_flag(frow(fH0, t, wv) + g);   // publish h0_t (tile wv)

    // ---- host-only outputs, off the critical path ----
    if (t == SS - 1 && n16 < 8) {
#pragma unroll
      for (int r = 0; r < 4; ++r) {
        const int b = wv * 16 + q * 4 + r;
        hn[(size_t)b * HH + hcol] = hvl[r];
        cn[(size_t)b * HH + hcol] = cvl[r];
      }
    }
  }
}

__device__ __forceinline__ void run_l1(
    const float* __restrict__ Wih, const float* __restrict__ Whh,
    const float* __restrict__ bih, const float* __restrict__ bhh,
    float* __restrict__ out1, float* __restrict__ hn, float* __restrict__ cn,
    const u16* __restrict__ R0, u16* __restrict__ R1,
    int* __restrict__ fH0, int* __restrict__ fH1, int* __restrict__ fC,
    u16* __restrict__ wcg)
{
  __shared__ u16 hT[4 * 16 * 8];      // 1KB
  __shared__ float oT[4 * 16 * 8];    // 2KB
  const int g = blockIdx.x & (NWG - 1);
  const int tid = threadIdx.x;
  const int wv = tid >> 6;
  const int lane = tid & 63;
  const int q = lane >> 4;
  const int n16 = lane & 15;
  const int g8 = g * 8;
  const int c0 = n16, c1 = 16 + n16;
  const int wrow0 = ((c0 >> 3) * HH) + g8 + (c0 & 7);
  const int wrow1 = ((c1 >> 3) * HH) + g8 + (c1 & 7);
  constexpr int KITER = 16;  // KIN = 512

  conv_weights<512>(Wih, Whh, wcg, wrow0, wrow1, q, lane, wv);
  __syncthreads();

  const float bias0 = bih[wrow0] + bhh[wrow0];
  const float bias1 = bih[wrow1] + bhh[wrow1];
  const int arow = wv * 16 + n16;
  const int hcol = g8 + n16;
  const int l16 = lane & 15;

  float cst[4] = {0.f, 0.f, 0.f, 0.f};
  float hvl[4], cvl[4];

  for (int t = 0; t < SS; ++t) {
    // ---- own recurrent h1_{t-1}: wait + issue loads first ----
    bf16x8 hf[16];
    if (t > 0) {
      waitflag_vec(frow(fH1, t - 1, wv));
      const u16* h1r = R1 + (size_t)((t - 1) & 1) * BB * HH
                     + (size_t)arow * HH + q * 8;
#pragma unroll
      for (int ks = 0; ks < 16; ++ks) hf[ks] = ldg_cv(h1r + ks * 32);
    }

    // ---- producer's h0_t, then its loads (h1 loads in flight) ----
    waitflag_vec(frow(fH0, t, wv));
    bf16x8 xf[16];
    const u16* h0r = R0 + (size_t)(t & (RDEPTH - 1)) * BB * HH
                   + (size_t)arow * HH + q * 8;
#pragma unroll
    for (int ks = 0; ks < 16; ++ks) xf[ks] = ldg_cv(h0r + ks * 32);
    VMCNT0();   // both h1 and h0 in registers
    if (lane == 0) set_flag(frow(fC, t, wv) + g);   // release h0 ring slot
    __builtin_amdgcn_sched_barrier(0);

    f32x4 acc0 = {0.f, 0.f, 0.f, 0.f};
    f32x4 acc1 = {0.f, 0.f, 0.f, 0.f};
#pragma unroll
    for (int ks = 0; ks < 16; ++ks) {
      bf16x8 b0 = ldfrag(wcg + ((size_t)(2 * ks + 0) * 64 + lane) * 8);
      bf16x8 b1 = ldfrag(wcg + ((size_t)(2 * ks + 1) * 64 + lane) * 8);
      acc0 = MFMA(xf[ks], b0, acc0);
      acc1 = MFMA(xf[ks], b1, acc1);
    }
    if (t > 0) {
#pragma unroll
      for (int ks = 0; ks < 16; ++ks) {
        bf16x8 b0 = ldfrag(wcg + ((size_t)(2 * (KITER + ks) + 0) * 64 + lane) * 8);
        bf16x8 b1 = ldfrag(wcg + ((size_t)(2 * (KITER + ks) + 1) * 64 + lane) * 8);
        acc0 = MFMA(hf[ks], b0, acc0);
        acc1 = MFMA(hf[ks], b1, acc1);
      }
    }

    float a0[4], a1[4], p0[4], p1[4];
#pragma unroll
    for (int r = 0; r < 4; ++r) { a0[r] = acc0[r] + bias0; a1[r] = acc1[r] + bias1; }
#pragma unroll
    for (int r = 0; r < 4; ++r) {
      p0[r] = __shfl_xor(a0[r], 8, 64);
      p1[r] = __shfl_xor(a1[r], 8, 64);
    }

    if (n16 < 8) {
#pragma unroll
      for (int r = 0; r < 4; ++r) {
        float ig = sigm(a0[r]);
        float fg = sigm(p0[r]);
        float gg = tanh_f(a1[r]);
        float og = sigm(p1[r]);
        float cv = fg * cst[r] + ig * gg;
        cst[r] = cv;
        float hv = og * tanh_f(cv);
        hvl[r] = hv; cvl[r] = cv;
        hT[wv * 128 + (q * 4 + r) * 8 + n16] = f2bf(hv);
        oT[wv * 128 + (q * 4 + r) * 8 + n16] = hv;
      }
    }
    LGKM0();

    // ---- coherent R1 ring store, drain, release ----
    if (lane < 16) {
      bf16x8 hv8 = *reinterpret_cast<bf16x8*>(&hT[wv * 128 + l16 * 8]);
      stg_cv(R1 + (size_t)(t & 1) * BB * HH
                + (size_t)(wv * 16 + l16) * HH + g8, hv8);
    }
    VMCNT0();
    if (lane == 0) set_flag(frow(fH1, t, wv) + g);

    // ---- out1: coalesced fp32 stores AFTER the release (host-only) ----
    if (lane < 32) {
      const int row = lane >> 1, half = lane & 1;
      f32x4 ov = *reinterpret_cast<f32x4*>(&oT[wv * 128 + row * 8 + half * 4]);
      const int b = wv * 16 + row;
      *reinterpret_cast<f32x4*>(out1 + ((size_t)b * SS + t) * HH + g8 + half * 4) = ov;
    }
    if (t == SS - 1 && n16 < 8) {
#pragma unroll
      for (int r = 0; r < 4; ++r) {
        const int b = wv * 16 + q * 4 + r;
        hn[(size_t)b * HH + hcol] = hvl[r];
        cn[(size_t)b * HH + hcol] = cvl[r];
      }
    }
  }
}

__global__ __launch_bounds__(256, 1) void lstm_persist(
    const float* __restrict__ x,
    const float* __restrict__ Wih0, const float* __restrict__ Whh0,
    const float* __restrict__ bih0, const float* __restrict__ bhh0,
    const float* __restrict__ Wih1, const float* __restrict__ Whh1,
    const float* __restrict__ bih1, const float* __restrict__ bhh1,
    float* out1, float* hn, float* cn,
    u16* R0, u16* R1,
    int* fH0, int* fH1, int* fC,
    u16* wc0, u16* wc1)
{
  const int g = blockIdx.x & (NWG - 1);
  if ((blockIdx.x >> 6) == 0) {
    run_l0(x, Wih0, Whh0, bih0, bhh0, hn, cn,
           R0, fH0, fC, wc0 + (size_t)g * 48 * 512);
  } else {
    run_l1(Wih1, Whh1, bih1, bhh1, out1,
           hn + (size_t)BB * HH, cn + (size_t)BB * HH,
           R0, R1, fH0, fH1, fC, wc1 + (size_t)g * 64 * 512);
  }
}

extern "C" void kernel_launch(void* const* d_in, const int* in_sizes, int n_in,
                              void* d_out, int out_size, void* d_ws, size_t ws_size,
                              hipStream_t stream) {
  const float* x    = (const float*)d_in[0];
  const float* Wih0 = (const float*)d_in[1];
  const float* Whh0 = (const float*)d_in[2];
  const float* bih0 = (const float*)d_in[3];
  const float* bhh0 = (const float*)d_in[4];
  const float* Wih1 = (const float*)d_in[5];
  const float* Whh1 = (const float*)d_in[6];
  const float* bih1 = (const float*)d_in[7];
  const float* bhh1 = (const float*)d_in[8];

  float* out  = (float*)d_out;
  float* out1 = out;                                  // (64,1024,512) fp32
  float* hn   = out + (size_t)BB * SS * HH;           // (2,64,512) fp32
  float* cn   = hn + 2 * (size_t)BB * HH;             // (2,64,512) fp32

  char* ws = (char*)d_ws;
  const size_t R0_B  = (size_t)RDEPTH * BB * HH * 2;  // 4 MiB: h0 ring
  const size_t R1_B  = 2ull * BB * HH * 2;            // 128 KiB: h1 ring
  const size_t F1_B  = (size_t)SS * 4 * 64 * 4;       // 1 MiB per flag array
  const size_t F_B   = 3 * F1_B;                      // fH0, fH1, fC
  const size_t WC0_B = (size_t)NWG * 48 * 512 * 2;    // 3 MiB frag cache L0
  const size_t WC1_B = (size_t)NWG * 64 * 512 * 2;    // 4 MiB frag cache L1
  if (ws_size < R0_B + R1_B + F_B + WC0_B + WC1_B) return;

  u16* R0  = (u16*)ws;
  u16* R1  = (u16*)(ws + R0_B);
  int* fH0 = (int*)(ws + R0_B + R1_B);
  int* fH1 = fH0 + (size_t)SS * 4 * 64;
  int* fC  = fH1 + (size_t)SS * 4 * 64;
  u16* wc0 = (u16*)(ws + R0_B + R1_B + F_B);
  u16* wc1 = wc0 + (size_t)NWG * 48 * 512;

  // zero the flags (rings need no init: t=0 skips recurrent reads)
  hipMemsetAsync(fH0, 0, F_B, stream);

  lstm_persist<<<dim3(2 * NWG), dim3(256), 0, stream>>>(
      x, Wih0, Whh0, bih0, bhh0, Wih1, Whh1, bih1, bhh1,
      out1, hn, cn, R0, R1, fH0, fH1, fC, wc0, wc1);
}

// Round 6
// 13108.057 us; speedup vs baseline: 1.6774x; 1.1582x over previous
//
#include <hip/hip_runtime.h>
#include <hip/hip_bf16.h>

// LSTM: B=64, S=1024, I=256, H=512, 2 layers. fp32 in/out.
// Persistent kernel, 128 worker WGs (64/layer) + 896 HEATER WGs.
// Round-6: DVFS experiment on the round-4 base (last green, 15.2ms).
//  Theory: rounds 0/1/4 (three different sync protocols) all sit at
//  15-22us/step because the near-idle GPU (VALUBusy 2.5%) is downclocked
//  by the power governor, multiplying every MALL round-trip on the serial
//  chain ~3x. Fix: keep the chip hot.
//   - 896 heater WGs spin dependent v_fmac chains (high clock residency,
//     low issue pressure), exit via rare MALL done-poll + hard cap
//   - worker flag polls: s_sleep backoff -> 128-fma heat burst
//   - fC ring gate amortized to 1 poll / 32 steps; L1 fH0 watermarked to
//     1 poll / 8 steps (L0 still publishes per step; in-order via VMCNT0)
//  Protocol, data layout, and numerics identical to round 4.

#define BB 64
#define SS 1024
#define HH 512
#define NWG 64      // WGs per layer
#define RDEPTH 64   // h0 ring depth (steps)

typedef unsigned short u16;
typedef __attribute__((ext_vector_type(8))) short bf16x8;
typedef __attribute__((ext_vector_type(4))) float f32x4;

__device__ __forceinline__ bf16x8 ldfrag(const u16* p) {
  return *reinterpret_cast<const bf16x8*>(p);
}
__device__ __forceinline__ u16 f2bf(float f) {
  __hip_bfloat16 h = __float2bfloat16(f);
  return *reinterpret_cast<u16*>(&h);
}
__device__ __forceinline__ bf16x8 cvt8(const float* p) {
  const f32x4* v = reinterpret_cast<const f32x4*>(p);
  f32x4 a = v[0], b = v[1];
  bf16x8 r;
  r[0] = (short)f2bf(a[0]); r[1] = (short)f2bf(a[1]);
  r[2] = (short)f2bf(a[2]); r[3] = (short)f2bf(a[3]);
  r[4] = (short)f2bf(b[0]); r[5] = (short)f2bf(b[1]);
  r[6] = (short)f2bf(b[2]); r[7] = (short)f2bf(b[3]);
  return r;
}
__device__ __forceinline__ float sigm(float x) { return 1.0f / (1.0f + __expf(-x)); }
__device__ __forceinline__ float tanh_f(float x) { return 2.0f / (1.0f + __expf(-2.0f * x)) - 1.0f; }

// ---- MALL-coherent data access (scope-encoded cache bypass) ----
__device__ __forceinline__ bf16x8 ldg_cv(const u16* p) {
  bf16x8 r;
  asm volatile("global_load_dwordx4 %0, %1, off sc0 sc1"
               : "=v"(r) : "v"(p) : "memory");
  return r;
}
__device__ __forceinline__ void stg_cv(u16* p, bf16x8 v) {
  asm volatile("global_store_dwordx4 %0, %1, off sc0 sc1"
               :: "v"(p), "v"(v) : "memory");
}
// ---- vector flags: one word per producer, one wave-wide poll ----
__device__ __forceinline__ void set_flag(int* p) {
  int one = 1;
  asm volatile("global_store_dword %0, %1, off sc0 sc1"
               :: "v"(p), "v"(one) : "memory");
}
// dependent-fma heat burst: keeps the SIMD/power governor awake during waits
__device__ __forceinline__ void heatburst() {
  float f = 1.0f;
#pragma unroll
  for (int k = 0; k < 128; ++k)
    asm volatile("v_fmac_f32 %0, %1, %2" : "+v"(f) : "v"(1.0000001f), "v"(1.0e-9f));
  asm volatile("" :: "v"(f));   // keep live
}
__device__ __forceinline__ void waitflag_vec(const int* row) {
  const int lane = threadIdx.x & 63;
  const int* p = row + lane;          // lane i watches producer WG i
  for (int it = 0; it < (1 << 13); ++it) {   // bounded: fail, don't hang
    int v;
    asm volatile("global_load_dword %0, %1, off sc0 sc1"
                 : "=v"(v) : "v"(p) : "memory");
    asm volatile("s_waitcnt vmcnt(0)" ::: "memory");
    if (__all(v != 0)) return;
    heatburst();                      // backoff = heat, not sleep
  }
}
__device__ __forceinline__ int* frow(int* base, int t, int wv) {
  return base + ((size_t)(t * 4 + wv) << 6);   // 64 ints per (t,wv) row
}
#define VMCNT0() do { \
  asm volatile("s_waitcnt vmcnt(0)" ::: "memory"); \
  __builtin_amdgcn_sched_barrier(0); \
} while (0)
#define LGKM0() do { \
  asm volatile("s_waitcnt lgkmcnt(0)" ::: "memory"); \
  __builtin_amdgcn_sched_barrier(0); \
} while (0)

#define MFMA(a, b, c) __builtin_amdgcn_mfma_f32_16x16x32_bf16((a), (b), (c), 0, 0, 0)

// Convert this WG's weight slice fp32->bf16 into a GLOBAL fragment cache.
// Slot (iter, lane) holds exactly the 16B fragment lane `lane` reads for iter.
template<int KIN>
__device__ __forceinline__ void conv_weights(
    const float* __restrict__ Wih, const float* __restrict__ Whh,
    u16* __restrict__ wcg, int wrow0, int wrow1, int q, int lane, int wv)
{
  constexpr int KITER = KIN / 32;
  constexpr int ITERS = (KITER + 16) * 2;
  for (int iter = wv; iter < ITERS; iter += 4) {
    const int half = iter >> 1;
    const int wrow = (iter & 1) ? wrow1 : wrow0;
    const float* src = (half < KITER)
        ? (Wih + (size_t)wrow * KIN + half * 32 + q * 8)
        : (Whh + (size_t)wrow * HH + (half - KITER) * 32 + q * 8);
    bf16x8 f = cvt8(src);
    *reinterpret_cast<bf16x8*>(wcg + ((size_t)iter * 64 + lane) * 8) = f;
  }
}

// ---- heater: dependent v_fmac chains until workers signal done ----
__device__ void heater(const int* doneCnt) {
  const int lane = threadIdx.x & 63;
  float f = 1.0f + threadIdx.x * 1.0e-6f;
  for (int it = 0; it < (1 << 16); ++it) {     // hard cap ~25-30ms
#pragma unroll
    for (int k = 0; k < 256; ++k)
      asm volatile("v_fmac_f32 %0, %1, %2" : "+v"(f) : "v"(1.0000001f), "v"(1.0e-9f));
    if ((it & 255) == 0) {                     // rare MALL poll (~every 100us)
      int d = 0;
      if (lane == 0)
        asm volatile("global_load_dword %0, %1, off sc0 sc1"
                     : "=v"(d) : "v"(doneCnt) : "memory");
      asm volatile("s_waitcnt vmcnt(0)" ::: "memory");
      d = __shfl(d, 0, 64);
      if (d >= 2 * NWG) break;
    }
  }
  asm volatile("" :: "v"(f));
}

__device__ __forceinline__ void run_l0(
    const float* __restrict__ x,
    const float* __restrict__ Wih, const float* __restrict__ Whh,
    const float* __restrict__ bih, const float* __restrict__ bhh,
    float* __restrict__ hn, float* __restrict__ cn,
    u16* __restrict__ R0, int* __restrict__ fH0, int* __restrict__ fC,
    u16* __restrict__ wcg)
{
  __shared__ u16 hT[4 * 16 * 8];      // per-wave transpose staging (1KB)
  const int g = blockIdx.x & (NWG - 1);
  const int tid = threadIdx.x;
  const int wv = tid >> 6;
  const int lane = tid & 63;
  const int q = lane >> 4;
  const int n16 = lane & 15;
  const int g8 = g * 8;
  const int c0 = n16, c1 = 16 + n16;
  const int wrow0 = ((c0 >> 3) * HH) + g8 + (c0 & 7);
  const int wrow1 = ((c1 >> 3) * HH) + g8 + (c1 & 7);
  constexpr int KIN = 256, KITER = 8;

  conv_weights<KIN>(Wih, Whh, wcg, wrow0, wrow1, q, lane, wv);
  __syncthreads();

  const float bias0 = bih[wrow0] + bhh[wrow0];
  const float bias1 = bih[wrow1] + bhh[wrow1];
  const int arow = wv * 16 + n16;
  const int hcol = g8 + n16;      // valid for n16 < 8
  const int l16 = lane & 15;

  float cst[4] = {0.f, 0.f, 0.f, 0.f};
  float hvl[4], cvl[4];

  for (int t = 0; t < SS; ++t) {
    // ---- x loads + cvt (flag-independent) ----
    bf16x8 xa[KITER];
    const float* xp = x + (size_t)arow * SS * KIN + (size_t)t * KIN + q * 8;
#pragma unroll
    for (int ks = 0; ks < KITER; ++ks) xa[ks] = cvt8(xp + ks * 32);

    // ---- wait peers' h_{t-1} (one vector poll), issue coherent h loads ----
    bf16x8 hf[16];
    if (t > 0) {
      waitflag_vec(frow(fH0, t - 1, wv));
      const u16* hr = R0 + (size_t)((t - 1) & (RDEPTH - 1)) * BB * HH
                    + (size_t)arow * HH + q * 8;
#pragma unroll
      for (int ks = 0; ks < 16; ++ks) hf[ks] = ldg_cv(hr + ks * 32);
    }

    // ---- x GEMM (h loads in flight), frags from global cache ----
    f32x4 acc0 = {0.f, 0.f, 0.f, 0.f};
    f32x4 acc1 = {0.f, 0.f, 0.f, 0.f};
#pragma unroll
    for (int ks = 0; ks < KITER; ++ks) {
      bf16x8 b0 = ldfrag(wcg + ((size_t)(2 * ks + 0) * 64 + lane) * 8);
      bf16x8 b1 = ldfrag(wcg + ((size_t)(2 * ks + 1) * 64 + lane) * 8);
      acc0 = MFMA(xa[ks], b0, acc0);
      acc1 = MFMA(xa[ks], b1, acc1);
    }

    // ---- h GEMM ----
    if (t > 0) {
      VMCNT0();
#pragma unroll
      for (int ks = 0; ks < 16; ++ks) {
        bf16x8 b0 = ldfrag(wcg + ((size_t)(2 * (KITER + ks) + 0) * 64 + lane) * 8);
        bf16x8 b1 = ldfrag(wcg + ((size_t)(2 * (KITER + ks) + 1) * 64 + lane) * 8);
        acc0 = MFMA(hf[ks], b0, acc0);
        acc1 = MFMA(hf[ks], b1, acc1);
      }
    }

    // ---- gates / cell update ----
    float a0[4], a1[4], p0[4], p1[4];
#pragma unroll
    for (int r = 0; r < 4; ++r) { a0[r] = acc0[r] + bias0; a1[r] = acc1[r] + bias1; }
#pragma unroll
    for (int r = 0; r < 4; ++r) {
      p0[r] = __shfl_xor(a0[r], 8, 64);   // f pre-activations (for n16<8)
      p1[r] = __shfl_xor(a1[r], 8, 64);   // o pre-activations
    }

    if (n16 < 8) {
#pragma unroll
      for (int r = 0; r < 4; ++r) {
        float ig = sigm(a0[r]);
        float fg = sigm(p0[r]);
        float gg = tanh_f(a1[r]);
        float og = sigm(p1[r]);
        float cv = fg * cst[r] + ig * gg;
        cst[r] = cv;
        float hv = og * tanh_f(cv);
        hvl[r] = hv; cvl[r] = cv;
        hT[wv * 128 + (q * 4 + r) * 8 + n16] = f2bf(hv);
      }
    }
    LGKM0();   // per-wave: transpose writes visible to reader lanes

    // ---- ring-slot reuse gate, amortized to 1 poll / 32 steps ----
    // At t (t%32==0) require L1 done step t-33: L0 stores at u in [t,t+32)
    // overwrite slots of steps u-64 <= t-33, all consumed by then.
    if (t >= RDEPTH && (t & 31) == 0) waitflag_vec(frow(fC, t - 33, wv));

    // ---- coherent ring store: 16 x 16B per wave ----
    if (lane < 16) {
      bf16x8 hv8 = *reinterpret_cast<bf16x8*>(&hT[wv * 128 + l16 * 8]);
      stg_cv(R0 + (size_t)(t & (RDEPTH - 1)) * BB * HH
                + (size_t)(wv * 16 + l16) * HH + g8, hv8);
    }
    VMCNT0();                                        // stores acked at MALL
    if (lane == 0) set_flag(frow(fH0, t, wv) + g);   // publish h0_t (tile wv)

    // ---- host-only outputs, off the critical path ----
    if (t == SS - 1 && n16 < 8) {
#pragma unroll
      for (int r = 0; r < 4; ++r) {
        const int b = wv * 16 + q * 4 + r;
        hn[(size_t)b * HH + hcol] = hvl[r];
        cn[(size_t)b * HH + hcol] = cvl[r];
      }
    }
  }
}

__device__ __forceinline__ void run_l1(
    const float* __restrict__ Wih, const float* __restrict__ Whh,
    const float* __restrict__ bih, const float* __restrict__ bhh,
    float* __restrict__ out1, float* __restrict__ hn, float* __restrict__ cn,
    const u16* __restrict__ R0, u16* __restrict__ R1,
    int* __restrict__ fH0, int* __restrict__ fH1, int* __restrict__ fC,
    u16* __restrict__ wcg)
{
  __shared__ u16 hT[4 * 16 * 8];      // 1KB
  __shared__ float oT[4 * 16 * 8];    // 2KB
  const int g = blockIdx.x & (NWG - 1);
  const int tid = threadIdx.x;
  const int wv = tid >> 6;
  const int lane = tid & 63;
  const int q = lane >> 4;
  const int n16 = lane & 15;
  const int g8 = g * 8;
  const int c0 = n16, c1 = 16 + n16;
  const int wrow0 = ((c0 >> 3) * HH) + g8 + (c0 & 7);
  const int wrow1 = ((c1 >> 3) * HH) + g8 + (c1 & 7);
  constexpr int KITER = 16;  // KIN = 512

  conv_weights<512>(Wih, Whh, wcg, wrow0, wrow1, q, lane, wv);
  __syncthreads();

  const float bias0 = bih[wrow0] + bhh[wrow0];
  const float bias1 = bih[wrow1] + bhh[wrow1];
  const int arow = wv * 16 + n16;
  const int hcol = g8 + n16;
  const int l16 = lane & 15;

  float cst[4] = {0.f, 0.f, 0.f, 0.f};
  float hvl[4], cvl[4];
  int lastReady = -1;

  for (int t = 0; t < SS; ++t) {
    // ---- own recurrent h1_{t-1}: wait + issue loads first ----
    bf16x8 hf[16];
    if (t > 0) {
      waitflag_vec(frow(fH1, t - 1, wv));
      const u16* h1r = R1 + (size_t)((t - 1) & 1) * BB * HH
                     + (size_t)arow * HH + q * 8;
#pragma unroll
      for (int ks = 0; ks < 16; ++ks) hf[ks] = ldg_cv(h1r + ks * 32);
    }

    // ---- producer watermark: 1 MALL poll per 8 steps ----
    // fH0[r] set (after VMCNT0, in program order) => steps <= r stored.
    const int need = t | 7;            // <= 1023 always
    if (need > lastReady) {
      waitflag_vec(frow(fH0, need, wv));
      lastReady = need;
    }
    bf16x8 xf[16];
    const u16* h0r = R0 + (size_t)(t & (RDEPTH - 1)) * BB * HH
                   + (size_t)arow * HH + q * 8;
#pragma unroll
    for (int ks = 0; ks < 16; ++ks) xf[ks] = ldg_cv(h0r + ks * 32);
    VMCNT0();   // both h1 and h0 in registers
    if (lane == 0) set_flag(frow(fC, t, wv) + g);   // release h0 ring slot
    __builtin_amdgcn_sched_barrier(0);

    f32x4 acc0 = {0.f, 0.f, 0.f, 0.f};
    f32x4 acc1 = {0.f, 0.f, 0.f, 0.f};
#pragma unroll
    for (int ks = 0; ks < 16; ++ks) {
      bf16x8 b0 = ldfrag(wcg + ((size_t)(2 * ks + 0) * 64 + lane) * 8);
      bf16x8 b1 = ldfrag(wcg + ((size_t)(2 * ks + 1) * 64 + lane) * 8);
      acc0 = MFMA(xf[ks], b0, acc0);
      acc1 = MFMA(xf[ks], b1, acc1);
    }
    if (t > 0) {
#pragma unroll
      for (int ks = 0; ks < 16; ++ks) {
        bf16x8 b0 = ldfrag(wcg + ((size_t)(2 * (KITER + ks) + 0) * 64 + lane) * 8);
        bf16x8 b1 = ldfrag(wcg + ((size_t)(2 * (KITER + ks) + 1) * 64 + lane) * 8);
        acc0 = MFMA(hf[ks], b0, acc0);
        acc1 = MFMA(hf[ks], b1, acc1);
      }
    }

    float a0[4], a1[4], p0[4], p1[4];
#pragma unroll
    for (int r = 0; r < 4; ++r) { a0[r] = acc0[r] + bias0; a1[r] = acc1[r] + bias1; }
#pragma unroll
    for (int r = 0; r < 4; ++r) {
      p0[r] = __shfl_xor(a0[r], 8, 64);
      p1[r] = __shfl_xor(a1[r], 8, 64);
    }

    if (n16 < 8) {
#pragma unroll
      for (int r = 0; r < 4; ++r) {
        float ig = sigm(a0[r]);
        float fg = sigm(p0[r]);
        float gg = tanh_f(a1[r]);
        float og = sigm(p1[r]);
        float cv = fg * cst[r] + ig * gg;
        cst[r] = cv;
        float hv = og * tanh_f(cv);
        hvl[r] = hv; cvl[r] = cv;
        hT[wv * 128 + (q * 4 + r) * 8 + n16] = f2bf(hv);
        oT[wv * 128 + (q * 4 + r) * 8 + n16] = hv;
      }
    }
    LGKM0();

    // ---- coherent R1 ring store, drain, release ----
    if (lane < 16) {
      bf16x8 hv8 = *reinterpret_cast<bf16x8*>(&hT[wv * 128 + l16 * 8]);
      stg_cv(R1 + (size_t)(t & 1) * BB * HH
                + (size_t)(wv * 16 + l16) * HH + g8, hv8);
    }
    VMCNT0();
    if (lane == 0) set_flag(frow(fH1, t, wv) + g);

    // ---- out1: coalesced fp32 stores AFTER the release (host-only) ----
    if (lane < 32) {
      const int row = lane >> 1, half = lane & 1;
      f32x4 ov = *reinterpret_cast<f32x4*>(&oT[wv * 128 + row * 8 + half * 4]);
      const int b = wv * 16 + row;
      *reinterpret_cast<f32x4*>(out1 + ((size_t)b * SS + t) * HH + g8 + half * 4) = ov;
    }
    if (t == SS - 1 && n16 < 8) {
#pragma unroll
      for (int r = 0; r < 4; ++r) {
        const int b = wv * 16 + q * 4 + r;
        hn[(size_t)b * HH + hcol] = hvl[r];
        cn[(size_t)b * HH + hcol] = cvl[r];
      }
    }
  }
}

__global__ __launch_bounds__(256, 1) void lstm_persist(
    const float* __restrict__ x,
    const float* __restrict__ Wih0, const float* __restrict__ Whh0,
    const float* __restrict__ bih0, const float* __restrict__ bhh0,
    const float* __restrict__ Wih1, const float* __restrict__ Whh1,
    const float* __restrict__ bih1, const float* __restrict__ bhh1,
    float* out1, float* hn, float* cn,
    u16* R0, u16* R1,
    int* fH0, int* fH1, int* fC, int* doneCnt,
    u16* wc0, u16* wc1)
{
  if (blockIdx.x >= 2 * NWG) {      // heater blocks
    heater(doneCnt);
    return;
  }
  const int g = blockIdx.x & (NWG - 1);
  if ((blockIdx.x >> 6) == 0) {
    run_l0(x, Wih0, Whh0, bih0, bhh0, hn, cn,
           R0, fH0, fC, wc0 + (size_t)g * 48 * 512);
  } else {
    run_l1(Wih1, Whh1, bih1, bhh1, out1,
           hn + (size_t)BB * HH, cn + (size_t)BB * HH,
           R0, R1, fH0, fH1, fC, wc1 + (size_t)g * 64 * 512);
  }
  // signal heaters (also on abort paths: run_* always returns here)
  if (threadIdx.x == 0)
    __hip_atomic_fetch_add(doneCnt, 1, __ATOMIC_RELAXED,
                           __HIP_MEMORY_SCOPE_SYSTEM);
}

extern "C" void kernel_launch(void* const* d_in, const int* in_sizes, int n_in,
                              void* d_out, int out_size, void* d_ws, size_t ws_size,
                              hipStream_t stream) {
  const float* x    = (const float*)d_in[0];
  const float* Wih0 = (const float*)d_in[1];
  const float* Whh0 = (const float*)d_in[2];
  const float* bih0 = (const float*)d_in[3];
  const float* bhh0 = (const float*)d_in[4];
  const float* Wih1 = (const float*)d_in[5];
  const float* Whh1 = (const float*)d_in[6];
  const float* bih1 = (const float*)d_in[7];
  const float* bhh1 = (const float*)d_in[8];

  float* out  = (float*)d_out;
  float* out1 = out;                                  // (64,1024,512) fp32
  float* hn   = out + (size_t)BB * SS * HH;           // (2,64,512) fp32
  float* cn   = hn + 2 * (size_t)BB * HH;             // (2,64,512) fp32

  char* ws = (char*)d_ws;
  const size_t R0_B  = (size_t)RDEPTH * BB * HH * 2;  // 4 MiB: h0 ring
  const size_t R1_B  = 2ull * BB * HH * 2;            // 128 KiB: h1 ring
  const size_t F1_B  = (size_t)SS * 4 * 64 * 4;       // 1 MiB per flag array
  const size_t F_B   = 3 * F1_B + 256;                // fH0, fH1, fC, doneCnt
  const size_t WC0_B = (size_t)NWG * 48 * 512 * 2;    // 3 MiB frag cache L0
  const size_t WC1_B = (size_t)NWG * 64 * 512 * 2;    // 4 MiB frag cache L1
  if (ws_size < R0_B + R1_B + F_B + WC0_B + WC1_B) return;

  u16* R0   = (u16*)ws;
  u16* R1   = (u16*)(ws + R0_B);
  int* fH0  = (int*)(ws + R0_B + R1_B);
  int* fH1  = fH0 + (size_t)SS * 4 * 64;
  int* fC   = fH1 + (size_t)SS * 4 * 64;
  int* done = fC  + (size_t)SS * 4 * 64;
  u16* wc0  = (u16*)(ws + R0_B + R1_B + F_B);
  u16* wc1  = wc0 + (size_t)NWG * 48 * 512;

  // zero the flags + done counter (rings need no init: t=0 skips reads)
  hipMemsetAsync(fH0, 0, F_B, stream);

  lstm_persist<<<dim3(1024), dim3(256), 0, stream>>>(
      x, Wih0, Whh0, bih0, bhh0, Wih1, Whh1, bih1, bhh1,
      out1, hn, cn, R0, R1, fH0, fH1, fC, done, wc0, wc1);
}